// Round 15
// baseline (271.867 us; speedup 1.0000x reference)
//
#include <hip/hip_runtime.h>
#include <hip/hip_bf16.h>
#include <stdint.h>

#define B_TOT 262144

typedef __attribute__((ext_vector_type(8))) short bf8;
typedef __attribute__((ext_vector_type(4))) float f32x4;

__device__ __forceinline__ uint32_t f2bf(float x) {
  uint32_t u = __float_as_uint(x);
  return (u + 0x7fffu + ((u >> 16) & 1u)) >> 16;   // RTN-even
}
__device__ __forceinline__ uint32_t pkbf(float lo, float hi) {
  union { __hip_bfloat162 b; uint32_t u; } c;
  c.b = __float22bfloat162_rn(make_float2(lo, hi));
  return c.u;
}
__device__ __forceinline__ bf8 mkfrag(uint32_t w0, uint32_t w1, uint32_t w2, uint32_t w3) {
  union { uint32_t u[4]; bf8 v; } c;
  c.u[0] = w0; c.u[1] = w1; c.u[2] = w2; c.u[3] = w3;
  return c.v;
}

// ---------------- prep: adj counts, W frags (16x16x32 true k-map), W@a score vecs ----
// 16x16x32 frag k-mapping: lane l, elem e: k = (e&3) + 4*((l>>4)&3) + 16*(e>>2); spatial = l&15.
__global__ __launch_bounds__(256) void prep_kernel(
    const int* __restrict__ adj,
    const float* __restrict__ W1, const float* __restrict__ a1s, const float* __restrict__ a1d,
    const float* __restrict__ W2, const float* __restrict__ a2s, const float* __restrict__ a2d,
    const float* __restrict__ Wo1, const float* __restrict__ Wo2,
    uint32_t* __restrict__ cntp, uint16_t* __restrict__ W1F, uint16_t* __restrict__ W2F,
    uint16_t* __restrict__ Wo1F, uint16_t* __restrict__ Wo2F, float* __restrict__ wvec)
{
  const int gid = blockIdx.x * 256 + threadIdx.x;
  if (gid < B_TOT) {
    uint32_t cpv = 0;
    const int* ap = adj + (size_t)gid * 9;
    #pragma unroll
    for (int i = 0; i < 3; ++i)
      #pragma unroll
      for (int j = 0; j < 3; ++j) {
        uint32_t c = (uint32_t)ap[j * 3 + i] + (i == j ? 1u : 0u);  // adj^T + I
        cpv |= c << (2 * (3 * i + j));
      }
    cntp[gid] = cpv;
  }
  const int e = gid & 7, li = (gid >> 3) & 63;
  const int kf = (e & 3) + 4 * ((li >> 4) & 3) + 16 * (e >> 2);
  const int sp = li & 15;
  if (gid < 4096) {   // W1F [ks2][t4]
    const int f = gid >> 9, t = f & 3, ks = f >> 2;
    const int k = ks * 32 + kf, row = t * 16 + sp;
    W1F[gid] = (uint16_t)f2bf(k < 35 ? W1[k * 64 + row] : 0.f);
  }
  if (gid < 4096) {   // W2F [ks2][t4]
    const int f = gid >> 9, t = f & 3, ks = f >> 2;
    const int k = ks * 32 + kf, row = t * 16 + sp;
    W2F[gid] = (uint16_t)f2bf(W2[k * 64 + row]);
  }
  if (gid < 49152) {  // Wo1F [ks6][t16]
    const int f = gid >> 9, t = f & 15, ks = f >> 4;
    const int k = ks * 32 + kf, col = t * 16 + sp;
    Wo1F[gid] = (uint16_t)f2bf(Wo1[k * 256 + col]);
  }
  if (gid < 32768) {  // Wo2F [ks8][t8]
    const int f = gid >> 9, t = f & 7, ks = f >> 3;
    const int k = ks * 32 + kf, col = t * 16 + sp;
    Wo2F[gid] = (uint16_t)f2bf(Wo2[k * 128 + col]);
  }
  if (gid < 224) {    // score vectors: [0..63]=W1@a1s (pad0), [64..127]=W1@a1d, [128..191]=W2@a2s, [192..255]=W2@a2d
    if (gid < 48) {
      float s = 0.f; if (gid < 35) for (int d = 0; d < 64; ++d) s += W1[gid * 64 + d] * a1s[d];
      wvec[gid] = s;
    } else if (gid < 96) {
      const int k = gid - 48; float s = 0.f;
      if (k < 35) for (int d = 0; d < 64; ++d) s += W1[k * 64 + d] * a1d[d];
      wvec[64 + k] = s;
    } else if (gid < 160) {
      const int k = gid - 96; float s = 0.f;
      for (int d = 0; d < 64; ++d) s += W2[k * 64 + d] * a2s[d];
      wvec[128 + k] = s;
    } else {
      const int k = gid - 160; float s = 0.f;
      for (int d = 0; d < 64; ++d) s += W2[k * 64 + d] * a2d[d];
      wvec[192 + k] = s;
    }
  }
}

// --------- softmax helper: alpha[3][3] from reduced ss/sd + counts ----------
__device__ __forceinline__ void att_alpha(const float (&ss)[3], const float (&sd)[3],
                                          uint32_t cp, float (&al)[3][3])
{
  #pragma unroll
  for (int i = 0; i < 3; ++i) {
    float ev[3]; float mx = -1e30f;
    #pragma unroll
    for (int j = 0; j < 3; ++j) {
      float s = ss[j] + sd[i];
      s = fmaxf(s, 0.2f * s);              // leaky_relu 0.2
      ev[j] = s;
      int c = (cp >> (2 * (3 * i + j))) & 3;
      mx = fmaxf(mx, c ? s : -1e30f);
    }
    float sum = 0.f;
    #pragma unroll
    for (int j = 0; j < 3; ++j) {
      int c = (cp >> (2 * (3 * i + j))) & 3;
      float p = (float)c * __expf(ev[j] - mx);
      al[i][j] = p; sum += p;
    }
    float inv = 1.0f / sum;
    #pragma unroll
    for (int j = 0; j < 3; ++j) al[i][j] *= inv;
  }
}

// ---- fused: 16x16x32 tiling; wave=16 elems; block=64 elems; 4 waves/SIMD target ----
// LDS word buffers (aliased): h2 = [elem][feat2] stride 98 (feat2 = feat/2, 0..95);
// y1 = [elem][feat2] stride 130 (feat2 0..127). part: LN/dot partials.
__global__ __launch_bounds__(256, 4) void fused_kernel(
    const float* __restrict__ obs, const float* __restrict__ act,
    const uint32_t* __restrict__ cntp,
    const uint16_t* __restrict__ W1F, const uint16_t* __restrict__ W2F,
    const float* __restrict__ b1, const float* __restrict__ b2,
    const uint16_t* __restrict__ Wo1F, const float* __restrict__ bo1,
    const float* __restrict__ g1, const float* __restrict__ be1,
    const uint16_t* __restrict__ Wo2F, const float* __restrict__ bo2,
    const float* __restrict__ g2, const float* __restrict__ be2,
    const float* __restrict__ Wo3, const float* __restrict__ bo3,
    const float* __restrict__ wvec, float* __restrict__ out)
{
  __shared__ __align__(16) uint32_t buf[8320];   // 33,280 B (h2 6272 w / y1 8320 w aliased)
  __shared__ float part[1024];                   // 4 KB
  const int tid = threadIdx.x;
  const int l = tid & 63, g = l >> 4, cl = l & 15;
  const int w = tid >> 6;
  const int g4 = g * 4;
  const int eb = w * 16 + cl;                  // own elem in block
  const int e = blockIdx.x * 64 + eb;
  const uint32_t cp = cntp[e];
  const float* obs_e = obs + (size_t)e * 90;
  const float* act_e = act + (size_t)e * 15;

  // ===== GAT1: structured loads + f32 score dots; B = x (own elem col) =====
  bf8 xf0[3], xf1[3];
  float ss1[3], sd1[3];
  #pragma unroll
  for (int n = 0; n < 3; ++n) {
    const float* on = obs_e + n * 30;
    const float* an = act_e + n * 5;
    const float a0 = an[0], a1 = an[1], a2 = an[2], a3 = an[3], a4 = an[4];
    float2 r00 = *reinterpret_cast<const float2*>(on + g4);
    float2 r01 = *reinterpret_cast<const float2*>(on + g4 + 2);
    float2 r10 = *reinterpret_cast<const float2*>(on + 16 + g4);
    float2 r11 = *reinterpret_cast<const float2*>(on + (g == 3 ? 24 : 18 + g4)); // g3 dummy
    const float k6 = (g == 3) ? a0 : r11.x;    // k = 18+g4 .. or 30
    const float k7 = (g == 3) ? a1 : r11.y;    // k = 19+g4 .. or 31
    const float s0 = (g == 0) ? a2 : 0.f;      // k = 32..34 only on g==0
    const float s1 = (g == 0) ? a3 : 0.f;
    const float s2 = (g == 0) ? a4 : 0.f;
    float ss, sd;
    {
      float4 wS = *reinterpret_cast<const float4*>(wvec + g4);
      float4 wD = *reinterpret_cast<const float4*>(wvec + 64 + g4);
      ss = r00.x * wS.x + r00.y * wS.y; ss = fmaf(r01.x, wS.z, ss); ss = fmaf(r01.y, wS.w, ss);
      sd = r00.x * wD.x + r00.y * wD.y; sd = fmaf(r01.x, wD.z, sd); sd = fmaf(r01.y, wD.w, sd);
      wS = *reinterpret_cast<const float4*>(wvec + 16 + g4);
      wD = *reinterpret_cast<const float4*>(wvec + 80 + g4);
      ss = fmaf(r10.x, wS.x, ss); ss = fmaf(r10.y, wS.y, ss); ss = fmaf(k6, wS.z, ss); ss = fmaf(k7, wS.w, ss);
      sd = fmaf(r10.x, wD.x, sd); sd = fmaf(r10.y, wD.y, sd); sd = fmaf(k6, wD.z, sd); sd = fmaf(k7, wD.w, sd);
      wS = *reinterpret_cast<const float4*>(wvec + 32 + g4);
      wD = *reinterpret_cast<const float4*>(wvec + 96 + g4);
      ss = fmaf(s0, wS.x, ss); ss = fmaf(s1, wS.y, ss); ss = fmaf(s2, wS.z, ss);
      sd = fmaf(s0, wD.x, sd); sd = fmaf(s1, wD.y, sd); sd = fmaf(s2, wD.z, sd);
    }
    ss1[n] = ss; sd1[n] = sd;
    xf0[n] = mkfrag(pkbf(r00.x, r00.y), pkbf(r01.x, r01.y), pkbf(r10.x, r10.y), pkbf(k6, k7));
    xf1[n] = mkfrag(pkbf(s0, s1), pkbf(s2, 0.f), 0u, 0u);
  }
  f32x4 az[3][4];
  #pragma unroll
  for (int n = 0; n < 3; ++n)
    #pragma unroll
    for (int t = 0; t < 4; ++t)
      #pragma unroll
      for (int r = 0; r < 4; ++r) az[n][t][r] = 0.f;
  #pragma unroll
  for (int ks = 0; ks < 2; ++ks)
    #pragma unroll
    for (int t = 0; t < 4; ++t) {
      bf8 a = *reinterpret_cast<const bf8*>(W1F + (size_t)((ks * 4 + t) * 64 + l) * 8);
      #pragma unroll
      for (int n = 0; n < 3; ++n)
        az[n][t] = __builtin_amdgcn_mfma_f32_16x16x32_bf16(a, ks ? xf1[n] : xf0[n], az[n][t], 0, 0, 0);
    }
  #pragma unroll
  for (int n = 0; n < 3; ++n) {
    ss1[n] += __shfl_xor(ss1[n], 16); ss1[n] += __shfl_xor(ss1[n], 32);
    sd1[n] += __shfl_xor(sd1[n], 16); sd1[n] += __shfl_xor(sd1[n], 32);
  }

  // ===== attention1: ELU agg + next scores; pack -> Ph word-pairs =====
  uint32_t Ph[3][4][2];
  float ss2[3] = {0, 0, 0}, sd2[3] = {0, 0, 0};
  {
    float al[3][3];
    att_alpha(ss1, sd1, cp, al);
    #pragma unroll
    for (int t = 0; t < 4; ++t) {
      float4 b4 = *reinterpret_cast<const float4*>(b1 + t * 16 + g4);
      float4 s4 = *reinterpret_cast<const float4*>(wvec + 128 + t * 16 + g4);
      float4 d4 = *reinterpret_cast<const float4*>(wvec + 192 + t * 16 + g4);
      const float bv[4] = {b4.x, b4.y, b4.z, b4.w};
      const float sv[4] = {s4.x, s4.y, s4.z, s4.w};
      const float dv[4] = {d4.x, d4.y, d4.z, d4.w};
      #pragma unroll
      for (int i = 0; i < 3; ++i) {
        float hv[4];
        #pragma unroll
        for (int r = 0; r < 4; ++r) {
          float v = bv[r];
          v = fmaf(al[i][0], az[0][t][r], v);
          v = fmaf(al[i][1], az[1][t][r], v);
          v = fmaf(al[i][2], az[2][t][r], v);
          v = v > 0.f ? v : (__expf(v) - 1.f);   // ELU
          ss2[i] = fmaf(v, sv[r], ss2[i]);
          sd2[i] = fmaf(v, dv[r], sd2[i]);
          hv[r] = v;
        }
        Ph[i][t][0] = pkbf(hv[0], hv[1]);
        Ph[i][t][1] = pkbf(hv[2], hv[3]);
      }
    }
  }
  #pragma unroll
  for (int i = 0; i < 3; ++i) {
    ss2[i] += __shfl_xor(ss2[i], 16); ss2[i] += __shfl_xor(ss2[i], 32);
    sd2[i] += __shfl_xor(sd2[i], 16); sd2[i] += __shfl_xor(sd2[i], 32);
  }

  // ===== GAT2: B-frag = concat of two Ph tiles (C-row == B-k identity) =====
  f32x4 a2z[3][4];
  #pragma unroll
  for (int n = 0; n < 3; ++n)
    #pragma unroll
    for (int t = 0; t < 4; ++t)
      #pragma unroll
      for (int r = 0; r < 4; ++r) a2z[n][t][r] = 0.f;
  #pragma unroll
  for (int ks = 0; ks < 2; ++ks) {
    bf8 br[3];
    #pragma unroll
    for (int n = 0; n < 3; ++n)
      br[n] = mkfrag(Ph[n][2 * ks][0], Ph[n][2 * ks][1], Ph[n][2 * ks + 1][0], Ph[n][2 * ks + 1][1]);
    #pragma unroll
    for (int t = 0; t < 4; ++t) {
      bf8 aW = *reinterpret_cast<const bf8*>(W2F + (size_t)((ks * 4 + t) * 64 + l) * 8);
      #pragma unroll
      for (int n = 0; n < 3; ++n)
        a2z[n][t] = __builtin_amdgcn_mfma_f32_16x16x32_bf16(aW, br[n], a2z[n][t], 0, 0, 0);
    }
  }

  // ===== attention2: agg (no ELU) -> h2 LDS (uint2 word-pairs, stride 98) =====
  {
    float al[3][3];
    att_alpha(ss2, sd2, cp, al);
    #pragma unroll
    for (int t = 0; t < 4; ++t) {
      float4 b4 = *reinterpret_cast<const float4*>(b2 + t * 16 + g4);
      const float bv[4] = {b4.x, b4.y, b4.z, b4.w};
      #pragma unroll
      for (int i = 0; i < 3; ++i) {
        float hv[4];
        #pragma unroll
        for (int r = 0; r < 4; ++r) {
          float v = bv[r];
          v = fmaf(al[i][0], a2z[0][t][r], v);
          v = fmaf(al[i][1], a2z[1][t][r], v);
          v = fmaf(al[i][2], a2z[2][t][r], v);
          hv[r] = v;
        }
        *reinterpret_cast<uint2*>(buf + eb * 98 + i * 32 + t * 8 + 2 * g) =
            make_uint2(pkbf(hv[0], hv[1]), pkbf(hv[2], hv[3]));
      }
    }
  }
  __syncthreads();                              // B1: h2 visible block-wide

  // ===== MLP1: wave w -> feat tiles w*4..w*4+3 (64 feats) for all 64 elems =====
  const int ft0 = w * 4;
  f32x4 acc[4][4];                              // [t][eg]
  #pragma unroll
  for (int t = 0; t < 4; ++t) {
    float4 b4 = *reinterpret_cast<const float4*>(bo1 + (ft0 + t) * 16 + g4);
    #pragma unroll
    for (int eg = 0; eg < 4; ++eg) {
      acc[t][eg][0] = b4.x; acc[t][eg][1] = b4.y; acc[t][eg][2] = b4.z; acc[t][eg][3] = b4.w;
    }
  }
  #pragma unroll
  for (int ks = 0; ks < 6; ++ks) {
    bf8 bfr[4];
    #pragma unroll
    for (int eg = 0; eg < 4; ++eg) {
      const uint32_t* p0 = buf + (eg * 16 + cl) * 98 + ks * 16 + 2 * g;
      uint2 u0 = *reinterpret_cast<const uint2*>(p0);
      uint2 u1 = *reinterpret_cast<const uint2*>(p0 + 8);
      bfr[eg] = mkfrag(u0.x, u0.y, u1.x, u1.y);
    }
    #pragma unroll
    for (int t = 0; t < 4; ++t) {
      bf8 a = *reinterpret_cast<const bf8*>(Wo1F + (size_t)((ks * 16 + ft0 + t) * 64 + l) * 8);
      #pragma unroll
      for (int eg = 0; eg < 4; ++eg)
        acc[t][eg] = __builtin_amdgcn_mfma_f32_16x16x32_bf16(a, bfr[eg], acc[t][eg], 0, 0, 0);
    }
  }
  // LN1 partials (wave's 64 feats per elem)
  {
    float psm[4] = {0, 0, 0, 0}, psq[4] = {0, 0, 0, 0};
    #pragma unroll
    for (int t = 0; t < 4; ++t)
      #pragma unroll
      for (int eg = 0; eg < 4; ++eg)
        #pragma unroll
        for (int r = 0; r < 4; ++r) {
          const float v = acc[t][eg][r]; psm[eg] += v; psq[eg] = fmaf(v, v, psq[eg]);
        }
    #pragma unroll
    for (int eg = 0; eg < 4; ++eg) {
      psm[eg] += __shfl_xor(psm[eg], 16); psm[eg] += __shfl_xor(psm[eg], 32);
      psq[eg] += __shfl_xor(psq[eg], 16); psq[eg] += __shfl_xor(psq[eg], 32);
      if (g == 0) {
        part[w * 64 + eg * 16 + cl] = psm[eg];
        part[256 + w * 64 + eg * 16 + cl] = psq[eg];
      }
    }
  }
  __syncthreads();                              // B2: partials visible; all h2 reads done
  float mu1[4], rr1[4];
  #pragma unroll
  for (int eg = 0; eg < 4; ++eg) {
    const int ei = eg * 16 + cl;
    float s = part[ei] + part[64 + ei] + part[128 + ei] + part[192 + ei];
    float q = part[256 + ei] + part[320 + ei] + part[384 + ei] + part[448 + ei];
    mu1[eg] = s * (1.f / 256.f);
    rr1[eg] = rsqrtf(q * (1.f / 256.f) - mu1[eg] * mu1[eg] + 1e-5f);
  }
  // LN1 apply + lrelu + pack -> y1 (stride 130; aliases h2, dead after B2)
  #pragma unroll
  for (int t = 0; t < 4; ++t) {
    float4 gg = *reinterpret_cast<const float4*>(g1 + (ft0 + t) * 16 + g4);
    float4 bb = *reinterpret_cast<const float4*>(be1 + (ft0 + t) * 16 + g4);
    const float gv[4] = {gg.x, gg.y, gg.z, gg.w};
    const float bv[4] = {bb.x, bb.y, bb.z, bb.w};
    #pragma unroll
    for (int eg = 0; eg < 4; ++eg) {
      float vv[4];
      #pragma unroll
      for (int r = 0; r < 4; ++r) {
        float v = (acc[t][eg][r] - mu1[eg]) * rr1[eg] * gv[r] + bv[r];
        vv[r] = fmaxf(v, 0.01f * v);
      }
      *reinterpret_cast<uint2*>(buf + (eg * 16 + cl) * 130 + (ft0 + t) * 8 + 2 * g) =
          make_uint2(pkbf(vv[0], vv[1]), pkbf(vv[2], vv[3]));
    }
  }
  __syncthreads();                              // B3: y1 complete

  // ===== MLP2: wave w -> feat tiles w*2..w*2+1 (32 feats) for all 64 elems =====
  const int ft2 = w * 2;
  f32x4 acc2[2][4];
  #pragma unroll
  for (int t = 0; t < 2; ++t) {
    float4 b4 = *reinterpret_cast<const float4*>(bo2 + (ft2 + t) * 16 + g4);
    #pragma unroll
    for (int eg = 0; eg < 4; ++eg) {
      acc2[t][eg][0] = b4.x; acc2[t][eg][1] = b4.y; acc2[t][eg][2] = b4.z; acc2[t][eg][3] = b4.w;
    }
  }
  #pragma unroll
  for (int ks = 0; ks < 8; ++ks) {
    bf8 bfr[4];
    #pragma unroll
    for (int eg = 0; eg < 4; ++eg) {
      const uint32_t* p0 = buf + (eg * 16 + cl) * 130 + ks * 16 + 2 * g;
      uint2 u0 = *reinterpret_cast<const uint2*>(p0);
      uint2 u1 = *reinterpret_cast<const uint2*>(p0 + 8);
      bfr[eg] = mkfrag(u0.x, u0.y, u1.x, u1.y);
    }
    #pragma unroll
    for (int t = 0; t < 2; ++t) {
      bf8 a = *reinterpret_cast<const bf8*>(Wo2F + (size_t)((ks * 8 + ft2 + t) * 64 + l) * 8);
      #pragma unroll
      for (int eg = 0; eg < 4; ++eg)
        acc2[t][eg] = __builtin_amdgcn_mfma_f32_16x16x32_bf16(a, bfr[eg], acc2[t][eg], 0, 0, 0);
    }
  }
  // LN2 partials (wave's 32 feats per elem)
  {
    float psm[4] = {0, 0, 0, 0}, psq[4] = {0, 0, 0, 0};
    #pragma unroll
    for (int t = 0; t < 2; ++t)
      #pragma unroll
      for (int eg = 0; eg < 4; ++eg)
        #pragma unroll
        for (int r = 0; r < 4; ++r) {
          const float v = acc2[t][eg][r]; psm[eg] += v; psq[eg] = fmaf(v, v, psq[eg]);
        }
    #pragma unroll
    for (int eg = 0; eg < 4; ++eg) {
      psm[eg] += __shfl_xor(psm[eg], 16); psm[eg] += __shfl_xor(psm[eg], 32);
      psq[eg] += __shfl_xor(psq[eg], 16); psq[eg] += __shfl_xor(psq[eg], 32);
      if (g == 0) {
        part[w * 64 + eg * 16 + cl] = psm[eg];
        part[256 + w * 64 + eg * 16 + cl] = psq[eg];
      }
    }
  }
  __syncthreads();                              // B4: LN2 partials visible
  {
    float dot[4];
    #pragma unroll
    for (int eg = 0; eg < 4; ++eg) {
      const int ei = eg * 16 + cl;
      float s = part[ei] + part[64 + ei] + part[128 + ei] + part[192 + ei];
      float q = part[256 + ei] + part[320 + ei] + part[384 + ei] + part[448 + ei];
      const float mu = s * (1.f / 128.f);
      const float rr = rsqrtf(q * (1.f / 128.f) - mu * mu + 1e-5f);
      float d = 0.f;
      #pragma unroll
      for (int t = 0; t < 2; ++t) {
        float4 gg = *reinterpret_cast<const float4*>(g2 + (ft2 + t) * 16 + g4);
        float4 bb = *reinterpret_cast<const float4*>(be2 + (ft2 + t) * 16 + g4);
        float4 ww = *reinterpret_cast<const float4*>(Wo3 + (ft2 + t) * 16 + g4);
        const float gv[4] = {gg.x, gg.y, gg.z, gg.w};
        const float bv[4] = {bb.x, bb.y, bb.z, bb.w};
        const float wv[4] = {ww.x, ww.y, ww.z, ww.w};
        #pragma unroll
        for (int r = 0; r < 4; ++r) {
          float v = (acc2[t][eg][r] - mu) * rr * gv[r] + bv[r];
          d = fmaf(fmaxf(v, 0.01f * v), wv[r], d);
        }
      }
      dot[eg] = d;
    }
    #pragma unroll
    for (int eg = 0; eg < 4; ++eg) {
      dot[eg] += __shfl_xor(dot[eg], 16); dot[eg] += __shfl_xor(dot[eg], 32);
      if (g == 0) part[512 + w * 64 + eg * 16 + cl] = dot[eg];
    }
  }
  __syncthreads();                              // B5: dot partials visible
  if (tid < 64) {
    out[blockIdx.x * 64 + tid] = part[512 + tid] + part[576 + tid] +
                                 part[640 + tid] + part[704 + tid] + bo3[0];
  }
}

extern "C" void kernel_launch(void* const* d_in, const int* in_sizes, int n_in,
                              void* d_out, int out_size, void* d_ws, size_t ws_size,
                              hipStream_t stream) {
  const float* obs  = (const float*)d_in[0];
  const float* actn = (const float*)d_in[1];
  const int*   adj  = (const int*)d_in[2];
  const float* W1   = (const float*)d_in[3];
  const float* a1s  = (const float*)d_in[4];
  const float* a1d  = (const float*)d_in[5];
  const float* b1   = (const float*)d_in[6];
  const float* W2   = (const float*)d_in[7];
  const float* a2s  = (const float*)d_in[8];
  const float* a2d  = (const float*)d_in[9];
  const float* b2   = (const float*)d_in[10];
  const float* Wo1  = (const float*)d_in[11];
  const float* bo1  = (const float*)d_in[12];
  const float* g1   = (const float*)d_in[13];
  const float* be1  = (const float*)d_in[14];
  const float* Wo2  = (const float*)d_in[15];
  const float* bo2  = (const float*)d_in[16];
  const float* g2   = (const float*)d_in[17];
  const float* be2  = (const float*)d_in[18];
  const float* Wo3  = (const float*)d_in[19];
  const float* bo3  = (const float*)d_in[20];

  char* ws = (char*)d_ws;
  uint32_t* cntp = (uint32_t*)ws;                       // 1 MB
  uint16_t* W1F  = (uint16_t*)(ws + 1048576);           // 8192 B
  uint16_t* W2F  = (uint16_t*)(ws + 1048576 + 8192);    // 8192 B
  uint16_t* Wo1F = (uint16_t*)(ws + 1048576 + 16384);   // 98304 B
  uint16_t* Wo2F = (uint16_t*)(ws + 1048576 + 114688);  // 65536 B
  float*    wvec = (float*)(ws + 1048576 + 180224);     // 1024 B
  float* outp = (float*)d_out;

  prep_kernel<<<1024, 256, 0, stream>>>(adj, W1, a1s, a1d, W2, a2s, a2d, Wo1, Wo2,
                                        cntp, W1F, W2F, Wo1F, Wo2F, wvec);
  fused_kernel<<<4096, 256, 0, stream>>>(obs, actn, cntp, W1F, W2F, b1, b2,
                                         Wo1F, bo1, g1, be1, Wo2F, bo2, g2, be2,
                                         Wo3, bo3, wvec, outp);
}

// Round 16
// 196.836 us; speedup vs baseline: 1.3812x; 1.3812x over previous
//
#include <hip/hip_runtime.h>
#include <hip/hip_bf16.h>
#include <stdint.h>

#define B_TOT 262144

typedef __attribute__((ext_vector_type(8))) short bf8;
typedef __attribute__((ext_vector_type(4))) float f32x4;

__device__ __forceinline__ uint32_t f2bf(float x) {
  uint32_t u = __float_as_uint(x);
  return (u + 0x7fffu + ((u >> 16) & 1u)) >> 16;   // RTN-even
}
__device__ __forceinline__ uint32_t pkbf(float lo, float hi) {
  union { __hip_bfloat162 b; uint32_t u; } c;
  c.b = __float22bfloat162_rn(make_float2(lo, hi));
  return c.u;
}
__device__ __forceinline__ bf8 mkfrag(uint32_t w0, uint32_t w1, uint32_t w2, uint32_t w3) {
  union { uint32_t u[4]; bf8 v; } c;
  c.u[0] = w0; c.u[1] = w1; c.u[2] = w2; c.u[3] = w3;
  return c.v;
}

// ---------------- prep: adj counts, W frags (16x16x32 true k-map), W@a score vecs ----
// 16x16x32 frag k-mapping: lane l, elem e: k = (e&3) + 4*((l>>4)&3) + 16*(e>>2); spatial = l&15.
__global__ __launch_bounds__(256) void prep_kernel(
    const int* __restrict__ adj,
    const float* __restrict__ W1, const float* __restrict__ a1s, const float* __restrict__ a1d,
    const float* __restrict__ W2, const float* __restrict__ a2s, const float* __restrict__ a2d,
    const float* __restrict__ Wo1, const float* __restrict__ Wo2,
    uint32_t* __restrict__ cntp, uint16_t* __restrict__ W1F, uint16_t* __restrict__ W2F,
    uint16_t* __restrict__ Wo1F, uint16_t* __restrict__ Wo2F, float* __restrict__ wvec)
{
  const int gid = blockIdx.x * 256 + threadIdx.x;
  if (gid < B_TOT) {
    uint32_t cpv = 0;
    const int* ap = adj + (size_t)gid * 9;
    #pragma unroll
    for (int i = 0; i < 3; ++i)
      #pragma unroll
      for (int j = 0; j < 3; ++j) {
        uint32_t c = (uint32_t)ap[j * 3 + i] + (i == j ? 1u : 0u);  // adj^T + I
        cpv |= c << (2 * (3 * i + j));
      }
    cntp[gid] = cpv;
  }
  const int e = gid & 7, li = (gid >> 3) & 63;
  const int kf = (e & 3) + 4 * ((li >> 4) & 3) + 16 * (e >> 2);
  const int sp = li & 15;
  if (gid < 4096) {   // W1F [ks2][t4]
    const int f = gid >> 9, t = f & 3, ks = f >> 2;
    const int k = ks * 32 + kf, row = t * 16 + sp;
    W1F[gid] = (uint16_t)f2bf(k < 35 ? W1[k * 64 + row] : 0.f);
  }
  if (gid < 4096) {   // W2F [ks2][t4]
    const int f = gid >> 9, t = f & 3, ks = f >> 2;
    const int k = ks * 32 + kf, row = t * 16 + sp;
    W2F[gid] = (uint16_t)f2bf(W2[k * 64 + row]);
  }
  if (gid < 49152) {  // Wo1F [ks6][t16]
    const int f = gid >> 9, t = f & 15, ks = f >> 4;
    const int k = ks * 32 + kf, col = t * 16 + sp;
    Wo1F[gid] = (uint16_t)f2bf(Wo1[k * 256 + col]);
  }
  if (gid < 32768) {  // Wo2F [ks8][t8]
    const int f = gid >> 9, t = f & 7, ks = f >> 3;
    const int k = ks * 32 + kf, col = t * 16 + sp;
    Wo2F[gid] = (uint16_t)f2bf(Wo2[k * 128 + col]);
  }
  if (gid < 224) {    // score vectors: [0..63]=W1@a1s (pad0), [64..127]=W1@a1d, [128..191]=W2@a2s, [192..255]=W2@a2d
    if (gid < 48) {
      float s = 0.f; if (gid < 35) for (int d = 0; d < 64; ++d) s += W1[gid * 64 + d] * a1s[d];
      wvec[gid] = s;
    } else if (gid < 96) {
      const int k = gid - 48; float s = 0.f;
      if (k < 35) for (int d = 0; d < 64; ++d) s += W1[k * 64 + d] * a1d[d];
      wvec[64 + k] = s;
    } else if (gid < 160) {
      const int k = gid - 96; float s = 0.f;
      for (int d = 0; d < 64; ++d) s += W2[k * 64 + d] * a2s[d];
      wvec[128 + k] = s;
    } else {
      const int k = gid - 160; float s = 0.f;
      for (int d = 0; d < 64; ++d) s += W2[k * 64 + d] * a2d[d];
      wvec[192 + k] = s;
    }
  }
}

// --------- softmax helper: alpha[3][3] from reduced ss/sd + counts ----------
__device__ __forceinline__ void att_alpha(const float (&ss)[3], const float (&sd)[3],
                                          uint32_t cp, float (&al)[3][3])
{
  #pragma unroll
  for (int i = 0; i < 3; ++i) {
    float ev[3]; float mx = -1e30f;
    #pragma unroll
    for (int j = 0; j < 3; ++j) {
      float s = ss[j] + sd[i];
      s = fmaxf(s, 0.2f * s);              // leaky_relu 0.2
      ev[j] = s;
      int c = (cp >> (2 * (3 * i + j))) & 3;
      mx = fmaxf(mx, c ? s : -1e30f);
    }
    float sum = 0.f;
    #pragma unroll
    for (int j = 0; j < 3; ++j) {
      int c = (cp >> (2 * (3 * i + j))) & 3;
      float p = (float)c * __expf(ev[j] - mx);
      al[i][j] = p; sum += p;
    }
    float inv = 1.0f / sum;
    #pragma unroll
    for (int j = 0; j < 3; ++j) al[i][j] *= inv;
  }
}

// ---- fused: 16x16x32 tiling; wave=16 elems; block=64 elems; 3 waves/SIMD target ----
// LDS word buffers (aliased): h2 = [elem][feat2] stride 98 (feat2 = feat/2, 0..95);
// y1 = [elem][feat2] stride 130 (feat2 0..127). part: LN/dot partials.
__global__ __launch_bounds__(256, 3) void fused_kernel(
    const float* __restrict__ obs, const float* __restrict__ act,
    const uint32_t* __restrict__ cntp,
    const uint16_t* __restrict__ W1F, const uint16_t* __restrict__ W2F,
    const float* __restrict__ b1, const float* __restrict__ b2,
    const uint16_t* __restrict__ Wo1F, const float* __restrict__ bo1,
    const float* __restrict__ g1, const float* __restrict__ be1,
    const uint16_t* __restrict__ Wo2F, const float* __restrict__ bo2,
    const float* __restrict__ g2, const float* __restrict__ be2,
    const float* __restrict__ Wo3, const float* __restrict__ bo3,
    const float* __restrict__ wvec, float* __restrict__ out)
{
  __shared__ __align__(16) uint32_t buf[8320];   // 33,280 B (h2 6272 w / y1 8320 w aliased)
  __shared__ float part[1024];                   // 4 KB
  const int tid = threadIdx.x;
  const int l = tid & 63, g = l >> 4, cl = l & 15;
  const int w = tid >> 6;
  const int g4 = g * 4;
  const int eb = w * 16 + cl;                  // own elem in block
  const int e = blockIdx.x * 64 + eb;
  const uint32_t cp = cntp[e];
  const float* obs_e = obs + (size_t)e * 90;
  const float* act_e = act + (size_t)e * 15;

  // ===== GAT1: structured loads + f32 score dots; B = x (own elem col) =====
  bf8 xf0[3], xf1[3];
  float ss1[3], sd1[3];
  #pragma unroll
  for (int n = 0; n < 3; ++n) {
    const float* on = obs_e + n * 30;
    const float* an = act_e + n * 5;
    const float a0 = an[0], a1 = an[1], a2 = an[2], a3 = an[3], a4 = an[4];
    float2 r00 = *reinterpret_cast<const float2*>(on + g4);
    float2 r01 = *reinterpret_cast<const float2*>(on + g4 + 2);
    float2 r10 = *reinterpret_cast<const float2*>(on + 16 + g4);
    float2 r11 = *reinterpret_cast<const float2*>(on + (g == 3 ? 24 : 18 + g4)); // g3 dummy
    const float k6 = (g == 3) ? a0 : r11.x;    // k = 18+g4 .. or 30
    const float k7 = (g == 3) ? a1 : r11.y;    // k = 19+g4 .. or 31
    const float s0 = (g == 0) ? a2 : 0.f;      // k = 32..34 only on g==0
    const float s1 = (g == 0) ? a3 : 0.f;
    const float s2 = (g == 0) ? a4 : 0.f;
    float ss, sd;
    {
      float4 wS = *reinterpret_cast<const float4*>(wvec + g4);
      float4 wD = *reinterpret_cast<const float4*>(wvec + 64 + g4);
      ss = r00.x * wS.x + r00.y * wS.y; ss = fmaf(r01.x, wS.z, ss); ss = fmaf(r01.y, wS.w, ss);
      sd = r00.x * wD.x + r00.y * wD.y; sd = fmaf(r01.x, wD.z, sd); sd = fmaf(r01.y, wD.w, sd);
      wS = *reinterpret_cast<const float4*>(wvec + 16 + g4);
      wD = *reinterpret_cast<const float4*>(wvec + 80 + g4);
      ss = fmaf(r10.x, wS.x, ss); ss = fmaf(r10.y, wS.y, ss); ss = fmaf(k6, wS.z, ss); ss = fmaf(k7, wS.w, ss);
      sd = fmaf(r10.x, wD.x, sd); sd = fmaf(r10.y, wD.y, sd); sd = fmaf(k6, wD.z, sd); sd = fmaf(k7, wD.w, sd);
      wS = *reinterpret_cast<const float4*>(wvec + 32 + g4);
      wD = *reinterpret_cast<const float4*>(wvec + 96 + g4);
      ss = fmaf(s0, wS.x, ss); ss = fmaf(s1, wS.y, ss); ss = fmaf(s2, wS.z, ss);
      sd = fmaf(s0, wD.x, sd); sd = fmaf(s1, wD.y, sd); sd = fmaf(s2, wD.z, sd);
    }
    ss1[n] = ss; sd1[n] = sd;
    xf0[n] = mkfrag(pkbf(r00.x, r00.y), pkbf(r01.x, r01.y), pkbf(r10.x, r10.y), pkbf(k6, k7));
    xf1[n] = mkfrag(pkbf(s0, s1), pkbf(s2, 0.f), 0u, 0u);
  }
  f32x4 az[3][4];
  #pragma unroll
  for (int n = 0; n < 3; ++n)
    #pragma unroll
    for (int t = 0; t < 4; ++t)
      #pragma unroll
      for (int r = 0; r < 4; ++r) az[n][t][r] = 0.f;
  #pragma unroll
  for (int ks = 0; ks < 2; ++ks)
    #pragma unroll
    for (int t = 0; t < 4; ++t) {
      bf8 a = *reinterpret_cast<const bf8*>(W1F + (size_t)((ks * 4 + t) * 64 + l) * 8);
      #pragma unroll
      for (int n = 0; n < 3; ++n)
        az[n][t] = __builtin_amdgcn_mfma_f32_16x16x32_bf16(a, ks ? xf1[n] : xf0[n], az[n][t], 0, 0, 0);
    }
  #pragma unroll
  for (int n = 0; n < 3; ++n) {
    ss1[n] += __shfl_xor(ss1[n], 16); ss1[n] += __shfl_xor(ss1[n], 32);
    sd1[n] += __shfl_xor(sd1[n], 16); sd1[n] += __shfl_xor(sd1[n], 32);
  }

  // ===== attention1: ELU agg + next scores; pack -> Ph word-pairs =====
  uint32_t Ph[3][4][2];
  float ss2[3] = {0, 0, 0}, sd2[3] = {0, 0, 0};
  {
    float al[3][3];
    att_alpha(ss1, sd1, cp, al);
    #pragma unroll
    for (int t = 0; t < 4; ++t) {
      float4 b4 = *reinterpret_cast<const float4*>(b1 + t * 16 + g4);
      float4 s4 = *reinterpret_cast<const float4*>(wvec + 128 + t * 16 + g4);
      float4 d4 = *reinterpret_cast<const float4*>(wvec + 192 + t * 16 + g4);
      const float bv[4] = {b4.x, b4.y, b4.z, b4.w};
      const float sv[4] = {s4.x, s4.y, s4.z, s4.w};
      const float dv[4] = {d4.x, d4.y, d4.z, d4.w};
      #pragma unroll
      for (int i = 0; i < 3; ++i) {
        float hv[4];
        #pragma unroll
        for (int r = 0; r < 4; ++r) {
          float v = bv[r];
          v = fmaf(al[i][0], az[0][t][r], v);
          v = fmaf(al[i][1], az[1][t][r], v);
          v = fmaf(al[i][2], az[2][t][r], v);
          v = v > 0.f ? v : (__expf(v) - 1.f);   // ELU
          ss2[i] = fmaf(v, sv[r], ss2[i]);
          sd2[i] = fmaf(v, dv[r], sd2[i]);
          hv[r] = v;
        }
        Ph[i][t][0] = pkbf(hv[0], hv[1]);
        Ph[i][t][1] = pkbf(hv[2], hv[3]);
      }
    }
  }
  #pragma unroll
  for (int i = 0; i < 3; ++i) {
    ss2[i] += __shfl_xor(ss2[i], 16); ss2[i] += __shfl_xor(ss2[i], 32);
    sd2[i] += __shfl_xor(sd2[i], 16); sd2[i] += __shfl_xor(sd2[i], 32);
  }

  // ===== GAT2: B-frag = concat of two Ph tiles (C-row == B-k identity) =====
  f32x4 a2z[3][4];
  #pragma unroll
  for (int n = 0; n < 3; ++n)
    #pragma unroll
    for (int t = 0; t < 4; ++t)
      #pragma unroll
      for (int r = 0; r < 4; ++r) a2z[n][t][r] = 0.f;
  #pragma unroll
  for (int ks = 0; ks < 2; ++ks) {
    bf8 br[3];
    #pragma unroll
    for (int n = 0; n < 3; ++n)
      br[n] = mkfrag(Ph[n][2 * ks][0], Ph[n][2 * ks][1], Ph[n][2 * ks + 1][0], Ph[n][2 * ks + 1][1]);
    #pragma unroll
    for (int t = 0; t < 4; ++t) {
      bf8 aW = *reinterpret_cast<const bf8*>(W2F + (size_t)((ks * 4 + t) * 64 + l) * 8);
      #pragma unroll
      for (int n = 0; n < 3; ++n)
        a2z[n][t] = __builtin_amdgcn_mfma_f32_16x16x32_bf16(aW, br[n], a2z[n][t], 0, 0, 0);
    }
  }

  // ===== attention2: agg (no ELU) -> h2 LDS (uint2 word-pairs, stride 98) =====
  {
    float al[3][3];
    att_alpha(ss2, sd2, cp, al);
    #pragma unroll
    for (int t = 0; t < 4; ++t) {
      float4 b4 = *reinterpret_cast<const float4*>(b2 + t * 16 + g4);
      const float bv[4] = {b4.x, b4.y, b4.z, b4.w};
      #pragma unroll
      for (int i = 0; i < 3; ++i) {
        float hv[4];
        #pragma unroll
        for (int r = 0; r < 4; ++r) {
          float v = bv[r];
          v = fmaf(al[i][0], a2z[0][t][r], v);
          v = fmaf(al[i][1], a2z[1][t][r], v);
          v = fmaf(al[i][2], a2z[2][t][r], v);
          hv[r] = v;
        }
        *reinterpret_cast<uint2*>(buf + eb * 98 + i * 32 + t * 8 + 2 * g) =
            make_uint2(pkbf(hv[0], hv[1]), pkbf(hv[2], hv[3]));
      }
    }
  }
  __syncthreads();                              // B1: h2 visible block-wide

  // ===== MLP1: wave w -> feat tiles w*4..w*4+3 (64 feats) for all 64 elems =====
  const int ft0 = w * 4;
  f32x4 acc[4][4];                              // [t][eg]
  #pragma unroll
  for (int t = 0; t < 4; ++t) {
    float4 b4 = *reinterpret_cast<const float4*>(bo1 + (ft0 + t) * 16 + g4);
    #pragma unroll
    for (int eg = 0; eg < 4; ++eg) {
      acc[t][eg][0] = b4.x; acc[t][eg][1] = b4.y; acc[t][eg][2] = b4.z; acc[t][eg][3] = b4.w;
    }
  }
  #pragma unroll
  for (int ks = 0; ks < 6; ++ks) {
    bf8 bfr[4];
    #pragma unroll
    for (int eg = 0; eg < 4; ++eg) {
      const uint32_t* p0 = buf + (eg * 16 + cl) * 98 + ks * 16 + 2 * g;
      uint2 u0 = *reinterpret_cast<const uint2*>(p0);
      uint2 u1 = *reinterpret_cast<const uint2*>(p0 + 8);
      bfr[eg] = mkfrag(u0.x, u0.y, u1.x, u1.y);
    }
    #pragma unroll
    for (int t = 0; t < 4; ++t) {
      bf8 a = *reinterpret_cast<const bf8*>(Wo1F + (size_t)((ks * 16 + ft0 + t) * 64 + l) * 8);
      #pragma unroll
      for (int eg = 0; eg < 4; ++eg)
        acc[t][eg] = __builtin_amdgcn_mfma_f32_16x16x32_bf16(a, bfr[eg], acc[t][eg], 0, 0, 0);
    }
  }
  // LN1 partials (wave's 64 feats per elem)
  {
    float psm[4] = {0, 0, 0, 0}, psq[4] = {0, 0, 0, 0};
    #pragma unroll
    for (int t = 0; t < 4; ++t)
      #pragma unroll
      for (int eg = 0; eg < 4; ++eg)
        #pragma unroll
        for (int r = 0; r < 4; ++r) {
          const float v = acc[t][eg][r]; psm[eg] += v; psq[eg] = fmaf(v, v, psq[eg]);
        }
    #pragma unroll
    for (int eg = 0; eg < 4; ++eg) {
      psm[eg] += __shfl_xor(psm[eg], 16); psm[eg] += __shfl_xor(psm[eg], 32);
      psq[eg] += __shfl_xor(psq[eg], 16); psq[eg] += __shfl_xor(psq[eg], 32);
      if (g == 0) {
        part[w * 64 + eg * 16 + cl] = psm[eg];
        part[256 + w * 64 + eg * 16 + cl] = psq[eg];
      }
    }
  }
  __syncthreads();                              // B2: partials visible; all h2 reads done
  float mu1[4], rr1[4];
  #pragma unroll
  for (int eg = 0; eg < 4; ++eg) {
    const int ei = eg * 16 + cl;
    float s = part[ei] + part[64 + ei] + part[128 + ei] + part[192 + ei];
    float q = part[256 + ei] + part[320 + ei] + part[384 + ei] + part[448 + ei];
    mu1[eg] = s * (1.f / 256.f);
    rr1[eg] = rsqrtf(q * (1.f / 256.f) - mu1[eg] * mu1[eg] + 1e-5f);
  }
  // LN1 apply + lrelu + pack -> y1 (stride 130; aliases h2, dead after B2)
  #pragma unroll
  for (int t = 0; t < 4; ++t) {
    float4 gg = *reinterpret_cast<const float4*>(g1 + (ft0 + t) * 16 + g4);
    float4 bb = *reinterpret_cast<const float4*>(be1 + (ft0 + t) * 16 + g4);
    const float gv[4] = {gg.x, gg.y, gg.z, gg.w};
    const float bv[4] = {bb.x, bb.y, bb.z, bb.w};
    #pragma unroll
    for (int eg = 0; eg < 4; ++eg) {
      float vv[4];
      #pragma unroll
      for (int r = 0; r < 4; ++r) {
        float v = (acc[t][eg][r] - mu1[eg]) * rr1[eg] * gv[r] + bv[r];
        vv[r] = fmaxf(v, 0.01f * v);
      }
      *reinterpret_cast<uint2*>(buf + (eg * 16 + cl) * 130 + (ft0 + t) * 8 + 2 * g) =
          make_uint2(pkbf(vv[0], vv[1]), pkbf(vv[2], vv[3]));
    }
  }
  __syncthreads();                              // B3: y1 complete

  // ===== MLP2: wave w -> feat tiles w*2..w*2+1 (32 feats) for all 64 elems =====
  const int ft2 = w * 2;
  f32x4 acc2[2][4];
  #pragma unroll
  for (int t = 0; t < 2; ++t) {
    float4 b4 = *reinterpret_cast<const float4*>(bo2 + (ft2 + t) * 16 + g4);
    #pragma unroll
    for (int eg = 0; eg < 4; ++eg) {
      acc2[t][eg][0] = b4.x; acc2[t][eg][1] = b4.y; acc2[t][eg][2] = b4.z; acc2[t][eg][3] = b4.w;
    }
  }
  #pragma unroll
  for (int ks = 0; ks < 8; ++ks) {
    bf8 bfr[4];
    #pragma unroll
    for (int eg = 0; eg < 4; ++eg) {
      const uint32_t* p0 = buf + (eg * 16 + cl) * 130 + ks * 16 + 2 * g;
      uint2 u0 = *reinterpret_cast<const uint2*>(p0);
      uint2 u1 = *reinterpret_cast<const uint2*>(p0 + 8);
      bfr[eg] = mkfrag(u0.x, u0.y, u1.x, u1.y);
    }
    #pragma unroll
    for (int t = 0; t < 2; ++t) {
      bf8 a = *reinterpret_cast<const bf8*>(Wo2F + (size_t)((ks * 8 + ft2 + t) * 64 + l) * 8);
      #pragma unroll
      for (int eg = 0; eg < 4; ++eg)
        acc2[t][eg] = __builtin_amdgcn_mfma_f32_16x16x32_bf16(a, bfr[eg], acc2[t][eg], 0, 0, 0);
    }
  }
  // LN2 partials (wave's 32 feats per elem)
  {
    float psm[4] = {0, 0, 0, 0}, psq[4] = {0, 0, 0, 0};
    #pragma unroll
    for (int t = 0; t < 2; ++t)
      #pragma unroll
      for (int eg = 0; eg < 4; ++eg)
        #pragma unroll
        for (int r = 0; r < 4; ++r) {
          const float v = acc2[t][eg][r]; psm[eg] += v; psq[eg] = fmaf(v, v, psq[eg]);
        }
    #pragma unroll
    for (int eg = 0; eg < 4; ++eg) {
      psm[eg] += __shfl_xor(psm[eg], 16); psm[eg] += __shfl_xor(psm[eg], 32);
      psq[eg] += __shfl_xor(psq[eg], 16); psq[eg] += __shfl_xor(psq[eg], 32);
      if (g == 0) {
        part[w * 64 + eg * 16 + cl] = psm[eg];
        part[256 + w * 64 + eg * 16 + cl] = psq[eg];
      }
    }
  }
  __syncthreads();                              // B4: LN2 partials visible
  {
    float dot[4];
    #pragma unroll
    for (int eg = 0; eg < 4; ++eg) {
      const int ei = eg * 16 + cl;
      float s = part[ei] + part[64 + ei] + part[128 + ei] + part[192 + ei];
      float q = part[256 + ei] + part[320 + ei] + part[384 + ei] + part[448 + ei];
      const float mu = s * (1.f / 128.f);
      const float rr = rsqrtf(q * (1.f / 128.f) - mu * mu + 1e-5f);
      float d = 0.f;
      #pragma unroll
      for (int t = 0; t < 2; ++t) {
        float4 gg = *reinterpret_cast<const float4*>(g2 + (ft2 + t) * 16 + g4);
        float4 bb = *reinterpret_cast<const float4*>(be2 + (ft2 + t) * 16 + g4);
        float4 ww = *reinterpret_cast<const float4*>(Wo3 + (ft2 + t) * 16 + g4);
        const float gv[4] = {gg.x, gg.y, gg.z, gg.w};
        const float bv[4] = {bb.x, bb.y, bb.z, bb.w};
        const float wv[4] = {ww.x, ww.y, ww.z, ww.w};
        #pragma unroll
        for (int r = 0; r < 4; ++r) {
          float v = (acc2[t][eg][r] - mu) * rr * gv[r] + bv[r];
          d = fmaf(fmaxf(v, 0.01f * v), wv[r], d);
        }
      }
      dot[eg] = d;
    }
    #pragma unroll
    for (int eg = 0; eg < 4; ++eg) {
      dot[eg] += __shfl_xor(dot[eg], 16); dot[eg] += __shfl_xor(dot[eg], 32);
      if (g == 0) part[512 + w * 64 + eg * 16 + cl] = dot[eg];
    }
  }
  __syncthreads();                              // B5: dot partials visible
  if (tid < 64) {
    out[blockIdx.x * 64 + tid] = part[512 + tid] + part[576 + tid] +
                                 part[640 + tid] + part[704 + tid] + bo3[0];
  }
}

extern "C" void kernel_launch(void* const* d_in, const int* in_sizes, int n_in,
                              void* d_out, int out_size, void* d_ws, size_t ws_size,
                              hipStream_t stream) {
  const float* obs  = (const float*)d_in[0];
  const float* actn = (const float*)d_in[1];
  const int*   adj  = (const int*)d_in[2];
  const float* W1   = (const float*)d_in[3];
  const float* a1s  = (const float*)d_in[4];
  const float* a1d  = (const float*)d_in[5];
  const float* b1   = (const float*)d_in[6];
  const float* W2   = (const float*)d_in[7];
  const float* a2s  = (const float*)d_in[8];
  const float* a2d  = (const float*)d_in[9];
  const float* b2   = (const float*)d_in[10];
  const float* Wo1  = (const float*)d_in[11];
  const float* bo1  = (const float*)d_in[12];
  const float* g1   = (const float*)d_in[13];
  const float* be1  = (const float*)d_in[14];
  const float* Wo2  = (const float*)d_in[15];
  const float* bo2  = (const float*)d_in[16];
  const float* g2   = (const float*)d_in[17];
  const float* be2  = (const float*)d_in[18];
  const float* Wo3  = (const float*)d_in[19];
  const float* bo3  = (const float*)d_in[20];

  char* ws = (char*)d_ws;
  uint32_t* cntp = (uint32_t*)ws;                       // 1 MB
  uint16_t* W1F  = (uint16_t*)(ws + 1048576);           // 8192 B
  uint16_t* W2F  = (uint16_t*)(ws + 1048576 + 8192);    // 8192 B
  uint16_t* Wo1F = (uint16_t*)(ws + 1048576 + 16384);   // 98304 B
  uint16_t* Wo2F = (uint16_t*)(ws + 1048576 + 114688);  // 65536 B
  float*    wvec = (float*)(ws + 1048576 + 180224);     // 1024 B
  float* outp = (float*)d_out;

  prep_kernel<<<1024, 256, 0, stream>>>(adj, W1, a1s, a1d, W2, a2s, a2d, Wo1, Wo2,
                                        cntp, W1F, W2F, Wo1F, Wo2F, wvec);
  fused_kernel<<<4096, 256, 0, stream>>>(obs, actn, cntp, W1F, W2F, b1, b2,
                                         Wo1F, bo1, g1, be1, Wo2F, bo2, g2, be2,
                                         Wo3, bo3, wvec, outp);
}